// Round 26
// baseline (243.377 us; speedup 1.0000x reference)
//
#include <hip/hip_runtime.h>
#include <hip/hip_bf16.h>
#include <math.h>

typedef unsigned short u16;
typedef __bf16 bf16x8 __attribute__((ext_vector_type(8)));
typedef float f32x4 __attribute__((ext_vector_type(4)));
typedef unsigned int u32x2 __attribute__((ext_vector_type(2)));

#define B_   2
#define T_   2048
#define D_   1024
#define H_   16
#define HD_  64
#define DFF_ 4096
#define M_TOK (B_*T_)

__device__ __forceinline__ u16 f2bf(float f){
  unsigned u = __float_as_uint(f);
  u += 0x7fff + ((u>>16)&1);          // round-nearest-even
  return (u16)(u>>16);
}
__device__ __forceinline__ float bflo(unsigned u){ return __uint_as_float(u<<16); }
__device__ __forceinline__ float bfhi(unsigned u){ return __uint_as_float(u & 0xffff0000u); }

__device__ __forceinline__ void gl2lds16(const void* g, void* l){
  __builtin_amdgcn_global_load_lds((const __attribute__((address_space(1))) void*)g,
                                   (__attribute__((address_space(3))) void*)l, 16, 0, 0);
}

__device__ __forceinline__ unsigned lds_u32(const void* p){
  return (unsigned)(uintptr_t)(const __attribute__((address_space(3))) void*)p;
}

__device__ __forceinline__ u32x2 tr_read(unsigned addr){
  u32x2 d;
  asm volatile("ds_read_b64_tr_b16 %0, %1" : "=v"(d) : "v"(addr));
  return d;
}
__device__ __forceinline__ u32x2 tr_read512(unsigned addr){
  u32x2 d;
  asm volatile("ds_read_b64_tr_b16 %0, %1 offset:512" : "=v"(d) : "v"(addr));
  return d;
}
__device__ __forceinline__ bf16x8 pack8(u32x2 a, u32x2 b){
  union { u32x2 u[2]; bf16x8 v; } x; x.u[0]=a; x.u[1]=b; return x.v;
}
__device__ __forceinline__ unsigned cvt_pk_bf16(float a, float b){
  unsigned r;
  asm("v_cvt_pk_bf16_f32 %0, %1, %2" : "=v"(r) : "v"(a), "v"(b));
  return r;
}
// fast GELU (tanh form)
__device__ __forceinline__ float gelu_fast(float v){
  float v2 = v*v;
  float u = v*fmaf(v2, 0.044715f, 1.0f);
  float e = exp2f(u*2.30220795f);
  return v - v/(e+1.0f);
}

// raw barrier with compiler fences (no vmcnt drain — counted waits done by caller)
__device__ __forceinline__ void block_barrier(){
  asm volatile("" ::: "memory");
  __builtin_amdgcn_s_barrier();
  __builtin_amdgcn_sched_barrier(0);
  asm volatile("" ::: "memory");
}

// m204 bijective XCD-chunk remap. orig -> logical.
__device__ __forceinline__ int xcd_chunk(int orig, int nwg){
  int q = nwg >> 3, r = nwg & 7;
  int x = orig & 7, s = orig >> 3;
  return (x < r ? x*(q+1) : r*(q+1) + (x-r)*q) + s;
}

// transpose one 32x32 tile using provided LDS buffer; tid256 in [0,256)
__device__ __forceinline__ void transpose_tile_b(float (*t)[33],
                                                 const float* __restrict__ in, u16* __restrict__ out,
                                                 int K, int N, int bxi, int byi, int tid256){
  int bx = bxi*32, by = byi*32;
  int tx = tid256&31, ty = tid256>>5;
  #pragma unroll
  for(int i=ty;i<32;i+=8) t[i][tx] = in[(size_t)(by+i)*N + bx + tx];
  __syncthreads();
  #pragma unroll
  for(int i=ty;i<32;i+=8) out[(size_t)(bx+i)*K + by + tx] = f2bf(t[tx][i]);
}

// ---------------- prologue: Wqkv transpose + RMSNorm-1 ----------------
__global__ __launch_bounds__(256) void k_prep(const float* __restrict__ Wqkv, u16* __restrict__ Wqkvt,
                                              const float* __restrict__ x, const float* __restrict__ scale1,
                                              u16* __restrict__ xn1){
  const int blk = blockIdx.x;
  const int tid = threadIdx.x;
  __shared__ float tbuf[32][33];
  if(blk < 3072){
    transpose_tile_b(tbuf, Wqkv, Wqkvt, D_, 3*D_, blk%96, blk/96, tid);
  } else {
    int row = blk - 3072;
    int lane = tid&63, wave = tid>>6;
    const float4* xr = (const float4*)(x + (size_t)row*D_);
    float4 v = xr[tid];
    float ss = v.x*v.x + v.y*v.y + v.z*v.z + v.w*v.w;
    #pragma unroll
    for(int o=1;o<64;o<<=1) ss += __shfl_xor(ss, o);
    __shared__ float red[4];
    if(lane==0) red[wave]=ss;
    __syncthreads();
    float tot = red[0]+red[1]+red[2]+red[3];
    float inv = 1.0f/(sqrtf(tot*(1.0f/D_)) + 1e-5f);
    float4 s4 = ((const float4*)scale1)[tid];
    u16* o4 = xn1 + (size_t)row*D_ + tid*4;
    o4[0]=f2bf(v.x*s4.x*inv); o4[1]=f2bf(v.y*s4.y*inv);
    o4[2]=f2bf(v.z*s4.z*inv); o4[3]=f2bf(v.w*s4.w*inv);
  }
}

// ---------------- QKV GEMM (192 blocks) + Wo/W1/W2 transposes co-gridded ----------------
__global__ __launch_bounds__(512,2) void k_qkv_prep2(const u16* __restrict__ A, const u16* __restrict__ Bt,
                                                     const float* __restrict__ bias, u16* __restrict__ Cout,
                                                     const float* __restrict__ Wo, u16* __restrict__ Wot,
                                                     const float* __restrict__ W1, u16* __restrict__ W1t,
                                                     const float* __restrict__ W2, u16* __restrict__ W2t){
  __shared__ u16 LDS[4][16384];
  const int tid = threadIdx.x;
  if(blockIdx.x >= 192){
    float (*tp)[33] = (float(*)[33])((char*)LDS + (tid>>8)*(32*33*4 + 64));
    int tile = (blockIdx.x - 192)*2 + (tid>>8);
    int tid256 = tid & 255;
    if(tile < 1024){
      transpose_tile_b(tp, Wo, Wot, D_, D_, tile%32, tile/32, tid256);
    } else if(tile < 5120){
      int t2 = tile - 1024;
      transpose_tile_b(tp, W1, W1t, D_, DFF_, t2%128, t2/128, tid256);
    } else {
      int t2 = tile - 5120;
      transpose_tile_b(tp, W2, W2t, DFF_, D_, t2%32, t2/32, tid256);
    }
    return;
  }
  const int N = 3*D_, K = D_;
  const int lane = tid&63, wave = tid>>6;
  const int lo = lane&15, hi = lane>>4;
  const int wm = wave>>2, wn = wave&3;
  const int l = xcd_chunk(blockIdx.x, 192);
  const int nbx = M_TOK/256;
  const int row0 = (l % nbx)*256;
  const int col0 = (l / nbx)*256;
  f32x4 acc[8][4];
  #pragma unroll
  for(int m=0;m<8;m++)
    #pragma unroll
    for(int n=0;n<4;n++) acc[m][n] = (f32x4){0.f,0.f,0.f,0.f};
  const u16* Ag = A + (size_t)row0*K;
  const u16* Bg = Bt + (size_t)col0*K;
  const int NT = K>>5;

  const int cc0 = tid, cc1 = tid+512;
  const size_t s0 = (size_t)(cc0>>2)*K + (size_t)((((cc0&3)^((cc0>>3)&3)))<<3);
  const size_t s1 = (size_t)(cc1>>2)*K + (size_t)((((cc1&3)^((cc1>>3)&3)))<<3);

  #define STAGE_A(t) { const u16* Ab = Ag + (size_t)(t)*32; char* d = (char*)LDS[(t)&3]; \
    gl2lds16(Ab + s0, d + cc0*16); gl2lds16(Ab + s1, d + cc1*16); }
  #define STAGE_B(t) { const u16* Bb = Bg + (size_t)(t)*32; char* d = (char*)LDS[(t)&3] + 16384; \
    gl2lds16(Bb + s0, d + cc0*16); gl2lds16(Bb + s1, d + cc1*16); }

  STAGE_A(0); STAGE_B(0); STAGE_A(1); STAGE_B(1); STAGE_A(2); STAGE_B(2);

  const unsigned slot = (unsigned)((hi ^ ((lo>>1)&3))<<4);
  for(int t=0;t<NT;t++){
    if(t<NT-2)       { asm volatile("s_waitcnt vmcnt(8)" ::: "memory"); }
    else if(t==NT-2) { asm volatile("s_waitcnt vmcnt(4)" ::: "memory"); }
    else             { asm volatile("s_waitcnt vmcnt(0)" ::: "memory"); }
    block_barrier();
    const char* bufp = (const char*)LDS[t&3];
    const char* ap = bufp + (wm*128 + lo)*64 + slot;
    const char* bp = bufp + 16384 + (wn*64 + lo)*64 + slot;

    if(t+3<NT) STAGE_A(t+3);
    __builtin_amdgcn_sched_barrier(0);
    bf16x8 a0[4], b[4];
    #pragma unroll
    for(int m=0;m<4;m++) a0[m] = *(const bf16x8*)(ap + m*1024);
    #pragma unroll
    for(int n=0;n<4;n++) b[n]  = *(const bf16x8*)(bp + n*1024);
    __builtin_amdgcn_s_setprio(1);
    #pragma unroll
    for(int m=0;m<4;m++)
      #pragma unroll
      for(int n=0;n<4;n++)
        acc[m][n] = __builtin_amdgcn_mfma_f32_16x16x32_bf16(a0[m], b[n], acc[m][n], 0,0,0);
    __builtin_amdgcn_s_setprio(0);

    if(t+3<NT) STAGE_B(t+3);
    __builtin_amdgcn_sched_barrier(0);
    bf16x8 a1[4];
    #pragma unroll
    for(int m=0;m<4;m++) a1[m] = *(const bf16x8*)(ap + 4096 + m*1024);
    __builtin_amdgcn_s_setprio(1);
    #pragma unroll
    for(int m=0;m<4;m++)
      #pragma unroll
      for(int n=0;n<4;n++)
        acc[m+4][n] = __builtin_amdgcn_mfma_f32_16x16x32_bf16(a1[m], b[n], acc[m+4][n], 0,0,0);
    __builtin_amdgcn_s_setprio(0);
  }
  #undef STAGE_A
  #undef STAGE_B

  #pragma unroll
  for(int m=0;m<8;m++){
    #pragma unroll
    for(int n=0;n<4;n++){
      #pragma unroll
      for(int r=0;r<4;r++){
        int row = row0 + wm*128 + m*16 + hi*4 + r;
        int col = col0 + wn*64 + n*16 + lo;
        float v = acc[m][n][r] + bias[col];
        Cout[(size_t)row*N + col] = f2bf(v);
      }
    }
  }
}

// ---------------- 256x256 deep-pipelined bf16 GEMM (split-K capable) ----------------
// EPI: 2 = gelu(bias)->bf16 ; 3 = bf16 partials (no bias), Cout=P base.
template<int EPI>
__global__ __launch_bounds__(512,2) void k_gemm256(const u16* __restrict__ A, const u16* __restrict__ Bt,
                                                   const float* __restrict__ bias,
                                                   void* __restrict__ Cout, int M, int N, int K,
                                                   int nbx, int nby, int splitk){
  __shared__ u16 LDS[4][16384];
  const int tid = threadIdx.x;
  const int lane = tid&63, wave = tid>>6;
  const int lo = lane&15, hi = lane>>4;
  const int wm = wave>>2, wn = wave&3;
  const int l = xcd_chunk(blockIdx.x, gridDim.x);
  const int row0 = (l % nbx)*256;
  const int col0 = ((l / nbx) % nby)*256;
  const int kc   = l / (nbx*nby);
  const int klen = K/splitk, kbeg = kc*klen;
  f32x4 acc[8][4];
  #pragma unroll
  for(int m=0;m<8;m++)
    #pragma unroll
    for(int n=0;n<4;n++) acc[m][n] = (f32x4){0.f,0.f,0.f,0.f};
  const u16* Ag = A + (size_t)row0*K + kbeg;
  const u16* Bg = Bt + (size_t)col0*K + kbeg;
  const int NT = klen>>5;

  const int cc0 = tid, cc1 = tid+512;
  const size_t s0 = (size_t)(cc0>>2)*K + (size_t)((((cc0&3)^((cc0>>3)&3)))<<3);
  const size_t s1 = (size_t)(cc1>>2)*K + (size_t)((((cc1&3)^((cc1>>3)&3)))<<3);

  #define STAGE_A(t) { const u16* Ab = Ag + (size_t)(t)*32; char* d = (char*)LDS[(t)&3]; \
    gl2lds16(Ab + s0, d + cc0*16); gl2lds16(Ab + s1, d + cc1*16); }
  #define STAGE_B(t) { const u16* Bb = Bg + (size_t)(t)*32; char* d = (char*)LDS[(t)&3] + 16384; \
    gl2lds16(Bb + s0, d + cc0*16); gl2lds16(Bb + s1, d + cc1*16); }

  STAGE_A(0); STAGE_B(0); STAGE_A(1); STAGE_B(1); STAGE_A(2); STAGE_B(2);

  const unsigned slot = (unsigned)((hi ^ ((lo>>1)&3))<<4);
  for(int t=0;t<NT;t++){
    if(t<NT-2)       { asm volatile("s_waitcnt vmcnt(8)" ::: "memory"); }
    else if(t==NT-2) { asm volatile("s_waitcnt vmcnt(4)" ::: "memory"); }
    else             { asm volatile("s_waitcnt vmcnt(0)" ::: "memory"); }
    block_barrier();
    const char* bufp = (const char*)LDS[t&3];
    const char* ap = bufp + (wm*128 + lo)*64 + slot;
    const char* bp = bufp + 16384 + (wn*64 + lo)*64 + slot;

    if(t+3<NT) STAGE_A(t+3);
    __builtin_amdgcn_sched_barrier(0);
    bf16x8 a0[4], b[4];
    #pragma unroll
    for(int m=0;m<4;m++) a0[m] = *(const bf16x8*)(ap + m*1024);
    #pragma unroll
    for(int n=0;n<4;n++) b[n]  = *(const bf16x8*)(bp + n*1024);
    __builtin_amdgcn_s_setprio(1);
    #pragma unroll
    for(int m=0;m<4;m++)
      #pragma unroll
      for(int n=0;n<4;n++)
        acc[m][n] = __builtin_amdgcn_mfma_f32_16x16x32_bf16(a0[m], b[n], acc[m][n], 0,0,0);
    __builtin_amdgcn_s_setprio(0);

    if(t+3<NT) STAGE_B(t+3);
    __builtin_amdgcn_sched_barrier(0);
    bf16x8 a1[4];
    #pragma unroll
    for(int m=0;m<4;m++) a1[m] = *(const bf16x8*)(ap + 4096 + m*1024);
    __builtin_amdgcn_s_setprio(1);
    #pragma unroll
    for(int m=0;m<4;m++)
      #pragma unroll
      for(int n=0;n<4;n++)
        acc[m+4][n] = __builtin_amdgcn_mfma_f32_16x16x32_bf16(a1[m], b[n], acc[m+4][n], 0,0,0);
    __builtin_amdgcn_s_setprio(0);
  }
  #undef STAGE_A
  #undef STAGE_B

  u16* Pk = (u16*)Cout + (size_t)kc*M*N;
  #pragma unroll
  for(int m=0;m<8;m++){
    #pragma unroll
    for(int n=0;n<4;n++){
      #pragma unroll
      for(int r=0;r<4;r++){
        int row = row0 + wm*128 + m*16 + hi*4 + r;
        int col = col0 + wn*64 + n*16 + lo;
        if constexpr(EPI==3){
          Pk[(size_t)row*N + col] = f2bf(acc[m][n][r]);
        } else {
          float v = acc[m][n][r] + bias[col];
          if constexpr(EPI==2){
            v = gelu_fast(v);
          }
          ((u16*)Cout)[(size_t)row*N + col] = f2bf(v);
        }
      }
    }
  }
}

// ---------------- FF2 pass 2: out = p0+p1+p2+p3 (bf16) + bias + res ----------------
__global__ __launch_bounds__(256) void k_ff2_reduce4(const u16* __restrict__ P,
                                                     const float* __restrict__ bias,
                                                     const float* __restrict__ res,
                                                     float* __restrict__ out){
  const size_t stride8 = (size_t)M_TOK*D_/8;
  size_t idx = (size_t)blockIdx.x*256 + threadIdx.x;
  const uint4* p = (const uint4*)P;
  uint4 q0 = p[idx], q1 = p[idx+stride8], q2 = p[idx+2*stride8], q3 = p[idx+3*stride8];
  size_t base = idx*8;
  const float4* rr = (const float4*)(res + base);
  const float4* bb = (const float4*)(bias + (base & (D_-1)));
  float4 r0 = rr[0], r1 = rr[1];
  float4 b0 = bb[0], b1 = bb[1];
  float4 o0, o1;
  unsigned w;
  w=q0.x; o0.x  = bflo(w); o0.y  = bfhi(w);
  w=q0.y; o0.z  = bflo(w); o0.w  = bfhi(w);
  w=q0.z; o1.x  = bflo(w); o1.y  = bfhi(w);
  w=q0.w; o1.z  = bflo(w); o1.w  = bfhi(w);
  w=q1.x; o0.x += bflo(w); o0.y += bfhi(w);
  w=q1.y; o0.z += bflo(w); o0.w += bfhi(w);
  w=q1.z; o1.x += bflo(w); o1.y += bfhi(w);
  w=q1.w; o1.z += bflo(w); o1.w += bfhi(w);
  w=q2.x; o0.x += bflo(w); o0.y += bfhi(w);
  w=q2.y; o0.z += bflo(w); o0.w += bfhi(w);
  w=q2.z; o1.x += bflo(w); o1.y += bfhi(w);
  w=q2.w; o1.z += bflo(w); o1.w += bfhi(w);
  w=q3.x; o0.x += bflo(w); o0.y += bfhi(w);
  w=q3.y; o0.z += bflo(w); o0.w += bfhi(w);
  w=q3.z; o1.x += bflo(w); o1.y += bfhi(w);
  w=q3.w; o1.z += bflo(w); o1.w += bfhi(w);
  o0.x += b0.x + r0.x; o0.y += b0.y + r0.y; o0.z += b0.z + r0.z; o0.w += b0.w + r0.w;
  o1.x += b1.x + r1.x; o1.y += b1.y + r1.y; o1.z += b1.z + r1.z; o1.w += b1.w + r1.w;
  float4* oo = (float4*)(out + base);
  oo[0] = o0; oo[1] = o1;
}

// ---------------- Wo pass 2 (4 partials) fused with RMSNorm-2 ----------------
__global__ __launch_bounds__(256) void k_wo_reduce_rms(const u16* __restrict__ P,
                                                       const float* __restrict__ bo,
                                                       const float* __restrict__ x,
                                                       const float* __restrict__ scale2,
                                                       float* __restrict__ x2,
                                                       u16* __restrict__ xn2){
  int row = blockIdx.x;
  int tid = threadIdx.x;
  int lane = tid&63, wave = tid>>6;
  const size_t stride = (size_t)M_TOK*D_;
  const u16* pr = P + (size_t)row*D_;
  uint2 a0 = ((const uint2*)pr)[tid];
  uint2 a1 = ((const uint2*)(pr + stride))[tid];
  uint2 a2 = ((const uint2*)(pr + 2*stride))[tid];
  uint2 a3 = ((const uint2*)(pr + 3*stride))[tid];
  float4 r = ((const float4*)(x + (size_t)row*D_))[tid];
  float4 bi = ((const float4*)bo)[tid];
  float4 v;
  v.x = bflo(a0.x)+bflo(a1.x)+bflo(a2.x)+bflo(a3.x) + bi.x + r.x;
  v.y = bfhi(a0.x)+bfhi(a1.x)+bfhi(a2.x)+bfhi(a3.x) + bi.y + r.y;
  v.z = bflo(a0.y)+bflo(a1.y)+bflo(a2.y)+bflo(a3.y) + bi.z + r.z;
  v.w = bfhi(a0.y)+bfhi(a1.y)+bfhi(a2.y)+bfhi(a3.y) + bi.w + r.w;
  ((float4*)(x2 + (size_t)row*D_))[tid] = v;
  float ss = v.x*v.x + v.y*v.y + v.z*v.z + v.w*v.w;
  #pragma unroll
  for(int o=1;o<64;o<<=1) ss += __shfl_xor(ss, o);
  __shared__ float red[4];
  if(lane==0) red[wave]=ss;
  __syncthreads();
  float tot = red[0]+red[1]+red[2]+red[3];
  float inv = 1.0f/(sqrtf(tot*(1.0f/D_)) + 1e-5f);
  float4 s4 = ((const float4*)scale2)[tid];
  u16* o4 = xn2 + (size_t)row*D_ + tid*4;
  o4[0]=f2bf(v.x*s4.x*inv); o4[1]=f2bf(v.y*s4.y*inv);
  o4[2]=f2bf(v.z*s4.z*inv); o4[3]=f2bf(v.w*s4.w*inv);
}

// ---------------- flash attention: 8 waves/block, single-drain PV (merged kk halves) ----
__global__ __launch_bounds__(512,4) void k_attn(const u16* __restrict__ qkv, u16* __restrict__ O){
  __shared__ alignas(16) u16 Ks[2][4096];
  __shared__ alignas(16) u16 Vs[2][4096];
  __shared__ alignas(16) u16 Ps[8][1024];
  const int l = xcd_chunk(blockIdx.x, 512);
  const int qt = l & 15, bh = l >> 4;
  const int h = bh & 15, b = bh >> 4;
  const int tid = threadIdx.x, lane = tid&63, wave = tid>>6;
  const int lo = lane&15, hi = lane>>4, l7 = lane&7;
  const u16* qkvB = qkv + (size_t)b*T_*3072;
  const int hoff = h*64;
  const float C2 = 0.18033688f;   // 0.125 * log2(e)

  const int q0 = qt*128 + wave*16;
  const u16* qp = qkvB + (size_t)(q0+lo)*3072 + hoff + hi*8;
  bf16x8 aq0 = *(const bf16x8*)qp;
  bf16x8 aq1 = *(const bf16x8*)(qp+32);

  size_t sK, sV;
  {
    int c = tid;
    sK = (size_t)(c>>3)*3072 + 1024 + hoff + (((c&7)^((c>>3)&7))<<3);
    int kv = ((c>>5)<<2) + ((c>>1)&3);
    int d0 = (((c&31)>>3)<<4) | ((c&1)<<3);
    sV = (size_t)kv*3072 + 2048 + hoff + d0;
  }
  const unsigned kb0 = (unsigned)lo*128 + (unsigned)((hi^l7))*16;
  const unsigned kb1 = (unsigned)lo*128 + (unsigned)(((hi|4)^l7))*16;
  const unsigned vtr = (unsigned)hi*1024 + (unsigned)lo*2;
  const unsigned swzQ = (unsigned)(lo&7)<<4;

  f32x4 oac[4];
  #pragma unroll
  for(int n=0;n<4;n++) oac[n] = (f32x4){0.f,0.f,0.f,0.f};
  float mrow = -1e30f;
  float lsum = 0.f;

  {
    gl2lds16(qkvB + sK, (char*)Ks[0] + tid*16);
    gl2lds16(qkvB + sV, (char*)Vs[0] + tid*16);
  }
  int buf = 0;
  for(int t=0;t<T_/64;t++){
    __syncthreads();
    if(t < T_/64-1){
      size_t koff = (size_t)(t+1)*64*3072;
      gl2lds16(qkvB + koff + sK, (char*)Ks[buf^1] + tid*16);
      gl2lds16(qkvB + koff + sV, (char*)Vs[buf^1] + tid*16);
    }
    const char* K_ = (const char*)Ks[buf];
    u16* P_ = Ps[wave];

    f32x4 s[4];
    #pragma unroll
    for(int n=0;n<4;n++){
      bf16x8 k0f = *(const bf16x8*)(K_ + n*2048 + kb0);
      bf16x8 k1f = *(const bf16x8*)(K_ + n*2048 + kb1);
      f32x4 z = (f32x4){0.f,0.f,0.f,0.f};
      z = __builtin_amdgcn_mfma_f32_16x16x32_bf16(k0f, aq0, z, 0,0,0);
      z = __builtin_amdgcn_mfma_f32_16x16x32_bf16(k1f, aq1, z, 0,0,0);
      s[n] = z;
    }

    float mx = s[0][0];
    #pragma unroll
    for(int n=0;n<4;n++)
      #pragma unroll
      for(int r=0;r<4;r++) mx = fmaxf(mx, s[n][r]);

    if(!__all(mx <= mrow + 64.0f)){
      float mm = fmaxf(mx, __shfl_xor(mx,16));
      mm = fmaxf(mm, __shfl_xor(mm,32));
      float nm = fmaxf(mrow, mm);
      float alpha = exp2f((mrow - nm)*C2);
      mrow = nm;
      lsum *= alpha;
      float ar[4];
      #pragma unroll
      for(int r=0;r<4;r++) ar[r] = __shfl(alpha, hi*4 + r);
      #pragma unroll
      for(int n=0;n<4;n++)
        #pragma unroll
        for(int r=0;r<4;r++) oac[n][r] *= ar[r];
    }

    const float nmC2 = -mrow*C2;
    #pragma unroll
    for(int n=0;n<4;n++){
      float p0v = exp2f(fmaf(s[n][0], C2, nmC2));
      float p1v = exp2f(fmaf(s[n][1], C2, nmC2));
      float p2v = exp2f(fmaf(s[n][2], C2, nmC2));
      float p3v = exp2f(fmaf(s[n][3], C2, nmC2));
      lsum += (p0v+p1v)+(p2v+p3v);
      u32x2 pw;
      pw[0] = cvt_pk_bf16(p0v, p1v);
      pw[1] = cvt_pk_bf16(p2v, p3v);
      *(u32x2*)((char*)P_ + (unsigned)lo*128 + (((unsigned)(n*32 + hi*8)) ^ swzQ)) = pw;
    }

    // PV: both kk halves batched -> single lgkmcnt drain per tile
    const unsigned vsb = lds_u32(Vs[buf]);
    {
      bf16x8 ap0 = *(const bf16x8*)((const char*)P_ + kb0);
      bf16x8 ap1 = *(const bf16x8*)((const char*)P_ + kb1);
      u32x2 t0[8], t1[8];
      #pragma unroll
      for(int kk=0;kk<2;kk++)
        #pragma unroll
        for(int n=0;n<4;n++){
          unsigned a = vsb + vtr + (unsigned)kk*4096 + (unsigned)n*128;
          t0[kk*4+n] = tr_read(a);
          t1[kk*4+n] = tr_read512(a);
        }
      asm volatile("s_waitcnt lgkmcnt(0)" ::: "memory");
      __builtin_amdgcn_sched_barrier(0);
      #pragma unroll
      for(int n=0;n<4;n++){
        bf16x8 bv = pack8(t0[n], t1[n]);
        oac[n] = __builtin_amdgcn_mfma_f32_16x16x32_bf16(ap0, bv, oac[n], 0,0,0);
      }
      #pragma unroll
      for(int n=0;n<4;n++){
        bf16x8 bv = pack8(t0[4+n], t1[4+n]);
        oac[n] = __builtin_amdgcn_mfma_f32_16x16x32_bf16(ap1, bv, oac[n], 0,0,0);
      }
    }
    buf ^= 1;
  }

  lsum += __shfl_xor(lsum, 16);
  lsum += __shfl_xor(lsum, 32);
  float linv = 1.0f/lsum;
  float lr[4];
  #pragma unroll
  for(int r=0;r<4;r++) lr[r] = __shfl(linv, hi*4 + r);
  size_t obase = ((size_t)b*T_ + q0)*D_ + hoff;
  #pragma unroll
  for(int n=0;n<4;n++)
    #pragma unroll
    for(int r=0;r<4;r++)
      O[obase + (size_t)(hi*4+r)*D_ + n*16 + lo] = f2bf(oac[n][r]*lr[r]);
}

extern "C" void kernel_launch(void* const* d_in, const int* in_sizes, int n_in,
                              void* d_out, int out_size, void* d_ws, size_t ws_size,
                              hipStream_t stream){
  (void)in_sizes; (void)n_in; (void)out_size; (void)ws_size;
  const float* x      = (const float*)d_in[0];
  const float* scale1 = (const float*)d_in[1];
  const float* scale2 = (const float*)d_in[2];
  const float* Wqkv   = (const float*)d_in[3];
  const float* bqkv   = (const float*)d_in[4];
  const float* Wo     = (const float*)d_in[5];
  const float* bo     = (const float*)d_in[6];
  const float* W1     = (const float*)d_in[7];
  const float* b1     = (const float*)d_in[8];
  const float* W2     = (const float*)d_in[9];
  const float* b2     = (const float*)d_in[10];
  float* out = (float*)d_out;

  char* w = (char*)d_ws;
  u16* xn1   = (u16*)w;  w += (size_t)M_TOK*D_*2;
  u16* qkvb  = (u16*)w;  w += (size_t)M_TOK*3*D_*2;
  u16* Obuf  = (u16*)w;  w += (size_t)M_TOK*D_*2;
  float* x2  = (float*)w; w += (size_t)M_TOK*D_*4;
  u16* xn2   = (u16*)w;  w += (size_t)M_TOK*D_*2;
  u16* h1    = (u16*)w;  w += (size_t)M_TOK*DFF_*2;
  u16* Wqkvt = (u16*)w;  w += (size_t)3*D_*D_*2;
  u16* Wot   = (u16*)w;  w += (size_t)D_*D_*2;
  u16* W1t   = (u16*)w;  w += (size_t)D_*DFF_*2;
  u16* W2t   = (u16*)w;  w += (size_t)DFF_*D_*2;
  // Split-K bf16 partials (4 x 8.39 MB) alias the d_ws head (xn1+qkvb = 33.6 MB):
  //  - Wo partials live [after attn .. wo_reduce] (xn1/qkvb dead after attn).
  //  - FF2 partials live [after FF1 .. ff2_reduce] (Wo partials dead).
  // Fully rewritten by their pass-1 each launch (deterministic).
  u16* wop = (u16*)d_ws;
  u16* pkb = (u16*)d_ws;

  k_prep<<<7168, 256, 0, stream>>>(Wqkv, Wqkvt, x, scale1, xn1);
  k_qkv_prep2<<<4800, 512, 0, stream>>>(xn1, Wqkvt, bqkv, qkvb, Wo, Wot, W1, W1t, W2, W2t);
  k_attn<<<512, 512, 0, stream>>>(qkvb, Obuf);
  k_gemm256<3><<<256, 512, 0, stream>>>(Obuf, Wot, nullptr, wop, M_TOK, D_, D_, M_TOK/256, D_/256, 4);
  k_wo_reduce_rms<<<M_TOK, 256, 0, stream>>>(wop, bo, x, scale2, x2, xn2);
  k_gemm256<2><<<256, 512, 0, stream>>>(xn2, W1t, b1, h1, M_TOK, DFF_, D_, M_TOK/256, DFF_/256, 1);
  k_gemm256<3><<<256, 512, 0, stream>>>(h1, W2t, nullptr, pkb, M_TOK, D_, DFF_, M_TOK/256, D_/256, 4);
  k_ff2_reduce4<<<2048, 256, 0, stream>>>(pkb, b2, x2, out);
}

// Round 27
// 242.021 us; speedup vs baseline: 1.0056x; 1.0056x over previous
//
#include <hip/hip_runtime.h>
#include <hip/hip_bf16.h>
#include <math.h>

typedef unsigned short u16;
typedef __bf16 bf16x8 __attribute__((ext_vector_type(8)));
typedef float f32x4 __attribute__((ext_vector_type(4)));
typedef unsigned int u32x2 __attribute__((ext_vector_type(2)));

#define B_   2
#define T_   2048
#define D_   1024
#define H_   16
#define HD_  64
#define DFF_ 4096
#define M_TOK (B_*T_)

__device__ __forceinline__ u16 f2bf(float f){
  unsigned u = __float_as_uint(f);
  u += 0x7fff + ((u>>16)&1);          // round-nearest-even
  return (u16)(u>>16);
}
__device__ __forceinline__ float bflo(unsigned u){ return __uint_as_float(u<<16); }
__device__ __forceinline__ float bfhi(unsigned u){ return __uint_as_float(u & 0xffff0000u); }

__device__ __forceinline__ void gl2lds16(const void* g, void* l){
  __builtin_amdgcn_global_load_lds((const __attribute__((address_space(1))) void*)g,
                                   (__attribute__((address_space(3))) void*)l, 16, 0, 0);
}

__device__ __forceinline__ unsigned lds_u32(const void* p){
  return (unsigned)(uintptr_t)(const __attribute__((address_space(3))) void*)p;
}

__device__ __forceinline__ u32x2 tr_read(unsigned addr){
  u32x2 d;
  asm volatile("ds_read_b64_tr_b16 %0, %1" : "=v"(d) : "v"(addr));
  return d;
}
__device__ __forceinline__ u32x2 tr_read512(unsigned addr){
  u32x2 d;
  asm volatile("ds_read_b64_tr_b16 %0, %1 offset:512" : "=v"(d) : "v"(addr));
  return d;
}
__device__ __forceinline__ bf16x8 pack8(u32x2 a, u32x2 b){
  union { u32x2 u[2]; bf16x8 v; } x; x.u[0]=a; x.u[1]=b; return x.v;
}
__device__ __forceinline__ unsigned cvt_pk_bf16(float a, float b){
  unsigned r;
  asm("v_cvt_pk_bf16_f32 %0, %1, %2" : "=v"(r) : "v"(a), "v"(b));
  return r;
}
// fast GELU (tanh form)
__device__ __forceinline__ float gelu_fast(float v){
  float v2 = v*v;
  float u = v*fmaf(v2, 0.044715f, 1.0f);
  float e = exp2f(u*2.30220795f);
  return v - v/(e+1.0f);
}

// raw barrier with compiler fences (no vmcnt drain — counted waits done by caller)
__device__ __forceinline__ void block_barrier(){
  asm volatile("" ::: "memory");
  __builtin_amdgcn_s_barrier();
  __builtin_amdgcn_sched_barrier(0);
  asm volatile("" ::: "memory");
}

// m204 bijective XCD-chunk remap. orig -> logical.
__device__ __forceinline__ int xcd_chunk(int orig, int nwg){
  int q = nwg >> 3, r = nwg & 7;
  int x = orig & 7, s = orig >> 3;
  return (x < r ? x*(q+1) : r*(q+1) + (x-r)*q) + s;
}

// transpose one 32x32 tile using provided LDS buffer; tid256 in [0,256)
__device__ __forceinline__ void transpose_tile_b(float (*t)[33],
                                                 const float* __restrict__ in, u16* __restrict__ out,
                                                 int K, int N, int bxi, int byi, int tid256){
  int bx = bxi*32, by = byi*32;
  int tx = tid256&31, ty = tid256>>5;
  #pragma unroll
  for(int i=ty;i<32;i+=8) t[i][tx] = in[(size_t)(by+i)*N + bx + tx];
  __syncthreads();
  #pragma unroll
  for(int i=ty;i<32;i+=8) out[(size_t)(bx+i)*K + by + tx] = f2bf(t[tx][i]);
}

// ---------------- prologue: Wqkv transpose + RMSNorm-1 ----------------
__global__ __launch_bounds__(256) void k_prep(const float* __restrict__ Wqkv, u16* __restrict__ Wqkvt,
                                              const float* __restrict__ x, const float* __restrict__ scale1,
                                              u16* __restrict__ xn1){
  const int blk = blockIdx.x;
  const int tid = threadIdx.x;
  __shared__ float tbuf[32][33];
  if(blk < 3072){
    transpose_tile_b(tbuf, Wqkv, Wqkvt, D_, 3*D_, blk%96, blk/96, tid);
  } else {
    int row = blk - 3072;
    int lane = tid&63, wave = tid>>6;
    const float4* xr = (const float4*)(x + (size_t)row*D_);
    float4 v = xr[tid];
    float ss = v.x*v.x + v.y*v.y + v.z*v.z + v.w*v.w;
    #pragma unroll
    for(int o=1;o<64;o<<=1) ss += __shfl_xor(ss, o);
    __shared__ float red[4];
    if(lane==0) red[wave]=ss;
    __syncthreads();
    float tot = red[0]+red[1]+red[2]+red[3];
    float inv = 1.0f/(sqrtf(tot*(1.0f/D_)) + 1e-5f);
    float4 s4 = ((const float4*)scale1)[tid];
    u16* o4 = xn1 + (size_t)row*D_ + tid*4;
    o4[0]=f2bf(v.x*s4.x*inv); o4[1]=f2bf(v.y*s4.y*inv);
    o4[2]=f2bf(v.z*s4.z*inv); o4[3]=f2bf(v.w*s4.w*inv);
  }
}

// ---------------- QKV GEMM (192 blocks) + Wo/W1/W2 transposes co-gridded ----------------
__global__ __launch_bounds__(512,2) void k_qkv_prep2(const u16* __restrict__ A, const u16* __restrict__ Bt,
                                                     const float* __restrict__ bias, u16* __restrict__ Cout,
                                                     const float* __restrict__ Wo, u16* __restrict__ Wot,
                                                     const float* __restrict__ W1, u16* __restrict__ W1t,
                                                     const float* __restrict__ W2, u16* __restrict__ W2t){
  __shared__ u16 LDS[4][16384];
  const int tid = threadIdx.x;
  if(blockIdx.x >= 192){
    float (*tp)[33] = (float(*)[33])((char*)LDS + (tid>>8)*(32*33*4 + 64));
    int tile = (blockIdx.x - 192)*2 + (tid>>8);
    int tid256 = tid & 255;
    if(tile < 1024){
      transpose_tile_b(tp, Wo, Wot, D_, D_, tile%32, tile/32, tid256);
    } else if(tile < 5120){
      int t2 = tile - 1024;
      transpose_tile_b(tp, W1, W1t, D_, DFF_, t2%128, t2/128, tid256);
    } else {
      int t2 = tile - 5120;
      transpose_tile_b(tp, W2, W2t, DFF_, D_, t2%32, t2/32, tid256);
    }
    return;
  }
  const int N = 3*D_, K = D_;
  const int lane = tid&63, wave = tid>>6;
  const int lo = lane&15, hi = lane>>4;
  const int wm = wave>>2, wn = wave&3;
  const int l = xcd_chunk(blockIdx.x, 192);
  const int nbx = M_TOK/256;
  const int row0 = (l % nbx)*256;
  const int col0 = (l / nbx)*256;
  f32x4 acc[8][4];
  #pragma unroll
  for(int m=0;m<8;m++)
    #pragma unroll
    for(int n=0;n<4;n++) acc[m][n] = (f32x4){0.f,0.f,0.f,0.f};
  const u16* Ag = A + (size_t)row0*K;
  const u16* Bg = Bt + (size_t)col0*K;
  const int NT = K>>5;

  const int cc0 = tid, cc1 = tid+512;
  const size_t s0 = (size_t)(cc0>>2)*K + (size_t)((((cc0&3)^((cc0>>3)&3)))<<3);
  const size_t s1 = (size_t)(cc1>>2)*K + (size_t)((((cc1&3)^((cc1>>3)&3)))<<3);

  #define STAGE_A(t) { const u16* Ab = Ag + (size_t)(t)*32; char* d = (char*)LDS[(t)&3]; \
    gl2lds16(Ab + s0, d + cc0*16); gl2lds16(Ab + s1, d + cc1*16); }
  #define STAGE_B(t) { const u16* Bb = Bg + (size_t)(t)*32; char* d = (char*)LDS[(t)&3] + 16384; \
    gl2lds16(Bb + s0, d + cc0*16); gl2lds16(Bb + s1, d + cc1*16); }

  STAGE_A(0); STAGE_B(0); STAGE_A(1); STAGE_B(1); STAGE_A(2); STAGE_B(2);

  const unsigned slot = (unsigned)((hi ^ ((lo>>1)&3))<<4);
  for(int t=0;t<NT;t++){
    if(t<NT-2)       { asm volatile("s_waitcnt vmcnt(8)" ::: "memory"); }
    else if(t==NT-2) { asm volatile("s_waitcnt vmcnt(4)" ::: "memory"); }
    else             { asm volatile("s_waitcnt vmcnt(0)" ::: "memory"); }
    block_barrier();
    const char* bufp = (const char*)LDS[t&3];
    const char* ap = bufp + (wm*128 + lo)*64 + slot;
    const char* bp = bufp + 16384 + (wn*64 + lo)*64 + slot;

    if(t+3<NT) STAGE_A(t+3);
    __builtin_amdgcn_sched_barrier(0);
    bf16x8 a0[4], b[4];
    #pragma unroll
    for(int m=0;m<4;m++) a0[m] = *(const bf16x8*)(ap + m*1024);
    #pragma unroll
    for(int n=0;n<4;n++) b[n]  = *(const bf16x8*)(bp + n*1024);
    __builtin_amdgcn_s_setprio(1);
    #pragma unroll
    for(int m=0;m<4;m++)
      #pragma unroll
      for(int n=0;n<4;n++)
        acc[m][n] = __builtin_amdgcn_mfma_f32_16x16x32_bf16(a0[m], b[n], acc[m][n], 0,0,0);
    __builtin_amdgcn_s_setprio(0);

    if(t+3<NT) STAGE_B(t+3);
    __builtin_amdgcn_sched_barrier(0);
    bf16x8 a1[4];
    #pragma unroll
    for(int m=0;m<4;m++) a1[m] = *(const bf16x8*)(ap + 4096 + m*1024);
    __builtin_amdgcn_s_setprio(1);
    #pragma unroll
    for(int m=0;m<4;m++)
      #pragma unroll
      for(int n=0;n<4;n++)
        acc[m+4][n] = __builtin_amdgcn_mfma_f32_16x16x32_bf16(a1[m], b[n], acc[m+4][n], 0,0,0);
    __builtin_amdgcn_s_setprio(0);
  }
  #undef STAGE_A
  #undef STAGE_B

  #pragma unroll
  for(int m=0;m<8;m++){
    #pragma unroll
    for(int n=0;n<4;n++){
      #pragma unroll
      for(int r=0;r<4;r++){
        int row = row0 + wm*128 + m*16 + hi*4 + r;
        int col = col0 + wn*64 + n*16 + lo;
        float v = acc[m][n][r] + bias[col];
        Cout[(size_t)row*N + col] = f2bf(v);
      }
    }
  }
}

// ---------------- 256x256 deep-pipelined bf16 GEMM (split-K capable) ----------------
// EPI: 2 = gelu(bias)->bf16 ; 3 = bf16 partials (no bias), Cout=P base.
template<int EPI>
__global__ __launch_bounds__(512,2) void k_gemm256(const u16* __restrict__ A, const u16* __restrict__ Bt,
                                                   const float* __restrict__ bias,
                                                   void* __restrict__ Cout, int M, int N, int K,
                                                   int nbx, int nby, int splitk){
  __shared__ u16 LDS[4][16384];
  const int tid = threadIdx.x;
  const int lane = tid&63, wave = tid>>6;
  const int lo = lane&15, hi = lane>>4;
  const int wm = wave>>2, wn = wave&3;
  const int l = xcd_chunk(blockIdx.x, gridDim.x);
  const int row0 = (l % nbx)*256;
  const int col0 = ((l / nbx) % nby)*256;
  const int kc   = l / (nbx*nby);
  const int klen = K/splitk, kbeg = kc*klen;
  f32x4 acc[8][4];
  #pragma unroll
  for(int m=0;m<8;m++)
    #pragma unroll
    for(int n=0;n<4;n++) acc[m][n] = (f32x4){0.f,0.f,0.f,0.f};
  const u16* Ag = A + (size_t)row0*K + kbeg;
  const u16* Bg = Bt + (size_t)col0*K + kbeg;
  const int NT = klen>>5;

  const int cc0 = tid, cc1 = tid+512;
  const size_t s0 = (size_t)(cc0>>2)*K + (size_t)((((cc0&3)^((cc0>>3)&3)))<<3);
  const size_t s1 = (size_t)(cc1>>2)*K + (size_t)((((cc1&3)^((cc1>>3)&3)))<<3);

  #define STAGE_A(t) { const u16* Ab = Ag + (size_t)(t)*32; char* d = (char*)LDS[(t)&3]; \
    gl2lds16(Ab + s0, d + cc0*16); gl2lds16(Ab + s1, d + cc1*16); }
  #define STAGE_B(t) { const u16* Bb = Bg + (size_t)(t)*32; char* d = (char*)LDS[(t)&3] + 16384; \
    gl2lds16(Bb + s0, d + cc0*16); gl2lds16(Bb + s1, d + cc1*16); }

  STAGE_A(0); STAGE_B(0); STAGE_A(1); STAGE_B(1); STAGE_A(2); STAGE_B(2);

  const unsigned slot = (unsigned)((hi ^ ((lo>>1)&3))<<4);
  for(int t=0;t<NT;t++){
    if(t<NT-2)       { asm volatile("s_waitcnt vmcnt(8)" ::: "memory"); }
    else if(t==NT-2) { asm volatile("s_waitcnt vmcnt(4)" ::: "memory"); }
    else             { asm volatile("s_waitcnt vmcnt(0)" ::: "memory"); }
    block_barrier();
    const char* bufp = (const char*)LDS[t&3];
    const char* ap = bufp + (wm*128 + lo)*64 + slot;
    const char* bp = bufp + 16384 + (wn*64 + lo)*64 + slot;

    if(t+3<NT) STAGE_A(t+3);
    __builtin_amdgcn_sched_barrier(0);
    bf16x8 a0[4], b[4];
    #pragma unroll
    for(int m=0;m<4;m++) a0[m] = *(const bf16x8*)(ap + m*1024);
    #pragma unroll
    for(int n=0;n<4;n++) b[n]  = *(const bf16x8*)(bp + n*1024);
    __builtin_amdgcn_s_setprio(1);
    #pragma unroll
    for(int m=0;m<4;m++)
      #pragma unroll
      for(int n=0;n<4;n++)
        acc[m][n] = __builtin_amdgcn_mfma_f32_16x16x32_bf16(a0[m], b[n], acc[m][n], 0,0,0);
    __builtin_amdgcn_s_setprio(0);

    if(t+3<NT) STAGE_B(t+3);
    __builtin_amdgcn_sched_barrier(0);
    bf16x8 a1[4];
    #pragma unroll
    for(int m=0;m<4;m++) a1[m] = *(const bf16x8*)(ap + 4096 + m*1024);
    __builtin_amdgcn_s_setprio(1);
    #pragma unroll
    for(int m=0;m<4;m++)
      #pragma unroll
      for(int n=0;n<4;n++)
        acc[m+4][n] = __builtin_amdgcn_mfma_f32_16x16x32_bf16(a1[m], b[n], acc[m+4][n], 0,0,0);
    __builtin_amdgcn_s_setprio(0);
  }
  #undef STAGE_A
  #undef STAGE_B

  u16* Pk = (u16*)Cout + (size_t)kc*M*N;
  #pragma unroll
  for(int m=0;m<8;m++){
    #pragma unroll
    for(int n=0;n<4;n++){
      #pragma unroll
      for(int r=0;r<4;r++){
        int row = row0 + wm*128 + m*16 + hi*4 + r;
        int col = col0 + wn*64 + n*16 + lo;
        if constexpr(EPI==3){
          Pk[(size_t)row*N + col] = f2bf(acc[m][n][r]);
        } else {
          float v = acc[m][n][r] + bias[col];
          if constexpr(EPI==2){
            v = gelu_fast(v);
          }
          ((u16*)Cout)[(size_t)row*N + col] = f2bf(v);
        }
      }
    }
  }
}

// ---------------- FF2 pass 2: out = p0+p1+p2+p3 (bf16) + bias + res ----------------
__global__ __launch_bounds__(256) void k_ff2_reduce4(const u16* __restrict__ P,
                                                     const float* __restrict__ bias,
                                                     const float* __restrict__ res,
                                                     float* __restrict__ out){
  const size_t stride8 = (size_t)M_TOK*D_/8;
  size_t idx = (size_t)blockIdx.x*256 + threadIdx.x;
  const uint4* p = (const uint4*)P;
  uint4 q0 = p[idx], q1 = p[idx+stride8], q2 = p[idx+2*stride8], q3 = p[idx+3*stride8];
  size_t base = idx*8;
  const float4* rr = (const float4*)(res + base);
  const float4* bb = (const float4*)(bias + (base & (D_-1)));
  float4 r0 = rr[0], r1 = rr[1];
  float4 b0 = bb[0], b1 = bb[1];
  float4 o0, o1;
  unsigned w;
  w=q0.x; o0.x  = bflo(w); o0.y  = bfhi(w);
  w=q0.y; o0.z  = bflo(w); o0.w  = bfhi(w);
  w=q0.z; o1.x  = bflo(w); o1.y  = bfhi(w);
  w=q0.w; o1.z  = bflo(w); o1.w  = bfhi(w);
  w=q1.x; o0.x += bflo(w); o0.y += bfhi(w);
  w=q1.y; o0.z += bflo(w); o0.w += bfhi(w);
  w=q1.z; o1.x += bflo(w); o1.y += bfhi(w);
  w=q1.w; o1.z += bflo(w); o1.w += bfhi(w);
  w=q2.x; o0.x += bflo(w); o0.y += bfhi(w);
  w=q2.y; o0.z += bflo(w); o0.w += bfhi(w);
  w=q2.z; o1.x += bflo(w); o1.y += bfhi(w);
  w=q2.w; o1.z += bflo(w); o1.w += bfhi(w);
  w=q3.x; o0.x += bflo(w); o0.y += bfhi(w);
  w=q3.y; o0.z += bflo(w); o0.w += bfhi(w);
  w=q3.z; o1.x += bflo(w); o1.y += bfhi(w);
  w=q3.w; o1.z += bflo(w); o1.w += bfhi(w);
  o0.x += b0.x + r0.x; o0.y += b0.y + r0.y; o0.z += b0.z + r0.z; o0.w += b0.w + r0.w;
  o1.x += b1.x + r1.x; o1.y += b1.y + r1.y; o1.z += b1.z + r1.z; o1.w += b1.w + r1.w;
  float4* oo = (float4*)(out + base);
  oo[0] = o0; oo[1] = o1;
}

// ---------------- Wo pass 2 (4 partials) fused with RMSNorm-2 ----------------
__global__ __launch_bounds__(256) void k_wo_reduce_rms(const u16* __restrict__ P,
                                                       const float* __restrict__ bo,
                                                       const float* __restrict__ x,
                                                       const float* __restrict__ scale2,
                                                       float* __restrict__ x2,
                                                       u16* __restrict__ xn2){
  int row = blockIdx.x;
  int tid = threadIdx.x;
  int lane = tid&63, wave = tid>>6;
  const size_t stride = (size_t)M_TOK*D_;
  const u16* pr = P + (size_t)row*D_;
  uint2 a0 = ((const uint2*)pr)[tid];
  uint2 a1 = ((const uint2*)(pr + stride))[tid];
  uint2 a2 = ((const uint2*)(pr + 2*stride))[tid];
  uint2 a3 = ((const uint2*)(pr + 3*stride))[tid];
  float4 r = ((const float4*)(x + (size_t)row*D_))[tid];
  float4 bi = ((const float4*)bo)[tid];
  float4 v;
  v.x = bflo(a0.x)+bflo(a1.x)+bflo(a2.x)+bflo(a3.x) + bi.x + r.x;
  v.y = bfhi(a0.x)+bfhi(a1.x)+bfhi(a2.x)+bfhi(a3.x) + bi.y + r.y;
  v.z = bflo(a0.y)+bflo(a1.y)+bflo(a2.y)+bflo(a3.y) + bi.z + r.z;
  v.w = bfhi(a0.y)+bfhi(a1.y)+bfhi(a2.y)+bfhi(a3.y) + bi.w + r.w;
  ((float4*)(x2 + (size_t)row*D_))[tid] = v;
  float ss = v.x*v.x + v.y*v.y + v.z*v.z + v.w*v.w;
  #pragma unroll
  for(int o=1;o<64;o<<=1) ss += __shfl_xor(ss, o);
  __shared__ float red[4];
  if(lane==0) red[wave]=ss;
  __syncthreads();
  float tot = red[0]+red[1]+red[2]+red[3];
  float inv = 1.0f/(sqrtf(tot*(1.0f/D_)) + 1e-5f);
  float4 s4 = ((const float4*)scale2)[tid];
  u16* o4 = xn2 + (size_t)row*D_ + tid*4;
  o4[0]=f2bf(v.x*s4.x*inv); o4[1]=f2bf(v.y*s4.y*inv);
  o4[2]=f2bf(v.z*s4.z*inv); o4[3]=f2bf(v.w*s4.w*inv);
}

// ---------------- flash attention: 8 waves/block, no setprio (lockstep structure) ------
__global__ __launch_bounds__(512,4) void k_attn(const u16* __restrict__ qkv, u16* __restrict__ O){
  __shared__ alignas(16) u16 Ks[2][4096];
  __shared__ alignas(16) u16 Vs[2][4096];
  __shared__ alignas(16) u16 Ps[8][1024];
  const int l = xcd_chunk(blockIdx.x, 512);
  const int qt = l & 15, bh = l >> 4;
  const int h = bh & 15, b = bh >> 4;
  const int tid = threadIdx.x, lane = tid&63, wave = tid>>6;
  const int lo = lane&15, hi = lane>>4, l7 = lane&7;
  const u16* qkvB = qkv + (size_t)b*T_*3072;
  const int hoff = h*64;
  const float C2 = 0.18033688f;   // 0.125 * log2(e)

  const int q0 = qt*128 + wave*16;
  const u16* qp = qkvB + (size_t)(q0+lo)*3072 + hoff + hi*8;
  bf16x8 aq0 = *(const bf16x8*)qp;
  bf16x8 aq1 = *(const bf16x8*)(qp+32);

  size_t sK, sV;
  {
    int c = tid;
    sK = (size_t)(c>>3)*3072 + 1024 + hoff + (((c&7)^((c>>3)&7))<<3);
    int kv = ((c>>5)<<2) + ((c>>1)&3);
    int d0 = (((c&31)>>3)<<4) | ((c&1)<<3);
    sV = (size_t)kv*3072 + 2048 + hoff + d0;
  }
  const unsigned kb0 = (unsigned)lo*128 + (unsigned)((hi^l7))*16;
  const unsigned kb1 = (unsigned)lo*128 + (unsigned)(((hi|4)^l7))*16;
  const unsigned vtr = (unsigned)hi*1024 + (unsigned)lo*2;
  const unsigned swzQ = (unsigned)(lo&7)<<4;

  f32x4 oac[4];
  #pragma unroll
  for(int n=0;n<4;n++) oac[n] = (f32x4){0.f,0.f,0.f,0.f};
  float mrow = -1e30f;
  float lsum = 0.f;

  {
    gl2lds16(qkvB + sK, (char*)Ks[0] + tid*16);
    gl2lds16(qkvB + sV, (char*)Vs[0] + tid*16);
  }
  int buf = 0;
  for(int t=0;t<T_/64;t++){
    __syncthreads();
    if(t < T_/64-1){
      size_t koff = (size_t)(t+1)*64*3072;
      gl2lds16(qkvB + koff + sK, (char*)Ks[buf^1] + tid*16);
      gl2lds16(qkvB + koff + sV, (char*)Vs[buf^1] + tid*16);
    }
    const char* K_ = (const char*)Ks[buf];
    u16* P_ = Ps[wave];

    f32x4 s[4];
    #pragma unroll
    for(int n=0;n<4;n++){
      bf16x8 k0f = *(const bf16x8*)(K_ + n*2048 + kb0);
      bf16x8 k1f = *(const bf16x8*)(K_ + n*2048 + kb1);
      f32x4 z = (f32x4){0.f,0.f,0.f,0.f};
      z = __builtin_amdgcn_mfma_f32_16x16x32_bf16(k0f, aq0, z, 0,0,0);
      z = __builtin_amdgcn_mfma_f32_16x16x32_bf16(k1f, aq1, z, 0,0,0);
      s[n] = z;
    }

    float mx = s[0][0];
    #pragma unroll
    for(int n=0;n<4;n++)
      #pragma unroll
      for(int r=0;r<4;r++) mx = fmaxf(mx, s[n][r]);

    if(!__all(mx <= mrow + 64.0f)){
      float mm = fmaxf(mx, __shfl_xor(mx,16));
      mm = fmaxf(mm, __shfl_xor(mm,32));
      float nm = fmaxf(mrow, mm);
      float alpha = exp2f((mrow - nm)*C2);
      mrow = nm;
      lsum *= alpha;
      float ar[4];
      #pragma unroll
      for(int r=0;r<4;r++) ar[r] = __shfl(alpha, hi*4 + r);
      #pragma unroll
      for(int n=0;n<4;n++)
        #pragma unroll
        for(int r=0;r<4;r++) oac[n][r] *= ar[r];
    }

    const float nmC2 = -mrow*C2;
    #pragma unroll
    for(int n=0;n<4;n++){
      float p0v = exp2f(fmaf(s[n][0], C2, nmC2));
      float p1v = exp2f(fmaf(s[n][1], C2, nmC2));
      float p2v = exp2f(fmaf(s[n][2], C2, nmC2));
      float p3v = exp2f(fmaf(s[n][3], C2, nmC2));
      lsum += (p0v+p1v)+(p2v+p3v);
      u32x2 pw;
      pw[0] = cvt_pk_bf16(p0v, p1v);
      pw[1] = cvt_pk_bf16(p2v, p3v);
      *(u32x2*)((char*)P_ + (unsigned)lo*128 + (((unsigned)(n*32 + hi*8)) ^ swzQ)) = pw;
    }

    const unsigned vsb = lds_u32(Vs[buf]);
    #pragma unroll
    for(int kk=0;kk<2;kk++){
      bf16x8 ap = *(const bf16x8*)((const char*)P_ + (kk==0 ? kb0 : kb1));
      u32x2 t0[4], t1[4];
      #pragma unroll
      for(int n=0;n<4;n++){
        unsigned a = vsb + vtr + (unsigned)kk*4096 + (unsigned)n*128;
        t0[n] = tr_read(a);
        t1[n] = tr_read512(a);
      }
      asm volatile("s_waitcnt lgkmcnt(0)" ::: "memory");
      __builtin_amdgcn_sched_barrier(0);
      #pragma unroll
      for(int n=0;n<4;n++){
        bf16x8 bv = pack8(t0[n], t1[n]);
        oac[n] = __builtin_amdgcn_mfma_f32_16x16x32_bf16(ap, bv, oac[n], 0,0,0);
      }
    }
    buf ^= 1;
  }

  lsum += __shfl_xor(lsum, 16);
  lsum += __shfl_xor(lsum, 32);
  float linv = 1.0f/lsum;
  float lr[4];
  #pragma unroll
  for(int r=0;r<4;r++) lr[r] = __shfl(linv, hi*4 + r);
  size_t obase = ((size_t)b*T_ + q0)*D_ + hoff;
  #pragma unroll
  for(int n=0;n<4;n++)
    #pragma unroll
    for(int r=0;r<4;r++)
      O[obase + (size_t)(hi*4+r)*D_ + n*16 + lo] = f2bf(oac[n][r]*lr[r]);
}

extern "C" void kernel_launch(void* const* d_in, const int* in_sizes, int n_in,
                              void* d_out, int out_size, void* d_ws, size_t ws_size,
                              hipStream_t stream){
  (void)in_sizes; (void)n_in; (void)out_size; (void)ws_size;
  const float* x      = (const float*)d_in[0];
  const float* scale1 = (const float*)d_in[1];
  const float* scale2 = (const float*)d_in[2];
  const float* Wqkv   = (const float*)d_in[3];
  const float* bqkv   = (const float*)d_in[4];
  const float* Wo     = (const float*)d_in[5];
  const float* bo     = (const float*)d_in[6];
  const float* W1     = (const float*)d_in[7];
  const float* b1     = (const float*)d_in[8];
  const float* W2     = (const float*)d_in[9];
  const float* b2     = (const float*)d_in[10];
  float* out = (float*)d_out;

  char* w = (char*)d_ws;
  u16* xn1   = (u16*)w;  w += (size_t)M_TOK*D_*2;
  u16* qkvb  = (u16*)w;  w += (size_t)M_TOK*3*D_*2;
  u16* Obuf  = (u16*)w;  w += (size_t)M_TOK*D_*2;
  float* x2  = (float*)w; w += (size_t)M_TOK*D_*4;
  u16* xn2   = (u16*)w;  w += (size_t)M_TOK*D_*2;
  u16* h1    = (u16*)w;  w += (size_t)M_TOK*DFF_*2;
  u16* Wqkvt = (u16*)w;  w += (size_t)3*D_*D_*2;
  u16* Wot   = (u16*)w;  w += (size_t)D_*D_*2;
  u16* W1t   = (u16*)w;  w += (size_t)D_*DFF_*2;
  u16* W2t   = (u16*)w;  w += (size_t)DFF_*D_*2;
  // Split-K bf16 partials (4 x 8.39 MB) alias the d_ws head (xn1+qkvb = 33.6 MB):
  //  - Wo partials live [after attn .. wo_reduce] (xn1/qkvb dead after attn).
  //  - FF2 partials live [after FF1 .. ff2_reduce] (Wo partials dead).
  // Fully rewritten by their pass-1 each launch (deterministic).
  u16* wop = (u16*)d_ws;
  u16* pkb = (u16*)d_ws;

  k_prep<<<7168, 256, 0, stream>>>(Wqkv, Wqkvt, x, scale1, xn1);
  k_qkv_prep2<<<4800, 512, 0, stream>>>(xn1, Wqkvt, bqkv, qkvb, Wo, Wot, W1, W1t, W2, W2t);
  k_attn<<<512, 512, 0, stream>>>(qkvb, Obuf);
  k_gemm256<3><<<256, 512, 0, stream>>>(Obuf, Wot, nullptr, wop, M_TOK, D_, D_, M_TOK/256, D_/256, 4);
  k_wo_reduce_rms<<<M_TOK, 256, 0, stream>>>(wop, bo, x, scale2, x2, xn2);
  k_gemm256<2><<<256, 512, 0, stream>>>(xn2, W1t, b1, h1, M_TOK, DFF_, D_, M_TOK/256, DFF_/256, 1);
  k_gemm256<3><<<256, 512, 0, stream>>>(h1, W2t, nullptr, pkb, M_TOK, D_, DFF_, M_TOK/256, D_/256, 4);
  k_ff2_reduce4<<<2048, 256, 0, stream>>>(pkb, b2, x2, out);
}